// Round 16
// baseline (108.586 us; speedup 1.0000x reference)
//
#include <hip/hip_runtime.h>
#include <math.h>
#include <stdint.h>

#define B_ 2
#define N_ 2048
#define D_ 1024
#define H_ 16
#define HD_ 64
#define M_ (B_ * N_)   // 4096

typedef __bf16 bf16x8 __attribute__((ext_vector_type(8)));
typedef float f32x4 __attribute__((ext_vector_type(4)));

__device__ __forceinline__ ushort bfbits(float f) {
    __bf16 h = (__bf16)f;
    return __builtin_bit_cast(ushort, h);
}

// async global->LDS, 16B per lane; LDS dest = wave-uniform base + lane*16
__device__ __forceinline__ void glds16(const ushort* g, ushort* l) {
    __builtin_amdgcn_global_load_lds(
        (const __attribute__((address_space(1))) uint32_t*)g,
        (__attribute__((address_space(3))) uint32_t*)l, 16, 0, 0);
}

// ---------------------------------------------------------------------------
// Prep: cvt_x (blocks 0..4095) + cvt_w transpose (blocks 4096..8191).
// ---------------------------------------------------------------------------
__global__ __launch_bounds__(256) void prep(const float* __restrict__ x,
                                            const float* __restrict__ W0,
                                            const float* __restrict__ W1,
                                            const float* __restrict__ W2,
                                            const float* __restrict__ W3,
                                            ushort* __restrict__ xb,
                                            ushort* __restrict__ Wt) {
    __shared__ float T[32][33];
    const int t = threadIdx.x;
    int id = blockIdx.x;
    if (id < 4096) {
        int i = id * 256 + t;
        float4 v = ((const float4*)x)[i];
        ushort4 o;
        o.x = bfbits(v.x); o.y = bfbits(v.y); o.z = bfbits(v.z); o.w = bfbits(v.w);
        ((ushort4*)xb)[i] = o;
        return;
    }
    id -= 4096;
    const int z = id >> 10;
    const int k0 = (id & 31) * 32, n0 = ((id >> 5) & 31) * 32;
    const float* W = (z == 0) ? W0 : (z == 1) ? W1 : (z == 2) ? W2 : W3;
    ushort* out = Wt + (size_t)z * D_ * D_;
    {
        int kl = t >> 3, nl = (t & 7) * 4;
        float4 v = *(const float4*)&W[(size_t)(k0 + kl) * D_ + n0 + nl];
        T[kl][nl] = v.x; T[kl][nl + 1] = v.y; T[kl][nl + 2] = v.z; T[kl][nl + 3] = v.w;
    }
    __syncthreads();
    {
        int nl = t >> 3, k4 = (t & 7) * 4;
        ushort4 o;
        o.x = bfbits(T[k4 + 0][nl]); o.y = bfbits(T[k4 + 1][nl]);
        o.z = bfbits(T[k4 + 2][nl]); o.w = bfbits(T[k4 + 3][nl]);
        *(ushort4*)&out[(size_t)(n0 + nl) * D_ + k0 + k4] = o;
    }
}

// ---------------------------------------------------------------------------
// MFMA GEMM mainloop (m97 structure): 128x128 tile, BK=32, linear LDS
// [128][32] bf16 staged via global_load_lds w=16, both-sides XOR swizzle.
// ---------------------------------------------------------------------------
#define BK 32

__device__ __forceinline__ void gemm_tile(const ushort* __restrict__ A,
                                          const ushort* __restrict__ Bt,
                                          int K, int tileM, int tileN,
                                          ushort* As, ushort* Bs,
                                          f32x4 acc[4][4]) {
    const int t = threadIdx.x;
    const int l = t & 63;
    const int w = __builtin_amdgcn_readfirstlane(t >> 6);
    const int wr = w >> 1, wc = w & 1;
    const int li = l & 15, lg = l >> 4;
    const int lr = l >> 2;
    const int colu = (((l & 3) ^ (lr & 3)) << 3);   // inverse-swizzled src col
    const int swz = (li & 3) << 3;                   // read-side xor

    for (int k0 = 0; k0 < K; k0 += BK) {
        __syncthreads();
        #pragma unroll
        for (int it = 0; it < 2; ++it) {
            const int c2 = it * 4 + w;
            const int row = c2 * 16 + lr;
            glds16(&A[(size_t)(tileM + row) * K + k0 + colu], &As[c2 * 512]);
            glds16(&Bt[(size_t)(tileN + row) * K + k0 + colu], &Bs[c2 * 512]);
        }
        __syncthreads();
        bf16x8 a[4], b[4];
        #pragma unroll
        for (int m = 0; m < 4; ++m)
            a[m] = *(const bf16x8*)&As[(wr * 64 + m * 16 + li) * 32 + ((lg << 3) ^ swz)];
        #pragma unroll
        for (int n = 0; n < 4; ++n)
            b[n] = *(const bf16x8*)&Bs[(wc * 64 + n * 16 + li) * 32 + ((lg << 3) ^ swz)];
        #pragma unroll
        for (int m = 0; m < 4; ++m)
            #pragma unroll
            for (int n = 0; n < 4; ++n)
                acc[m][n] = __builtin_amdgcn_mfma_f32_16x16x32_bf16(a[m], b[n], acc[m][n], 0, 0, 0);
    }
}

// ---------------------------------------------------------------------------
// QKV projection. Q,K -> plain [M][D] bf16 (Q pre-scaled by 0.125*log2e);
// V -> [B,H,HD,N] transposed directly from the epilogue.
// grid 768 flat, bijective XCD swizzle (768%8==0).
// ---------------------------------------------------------------------------
#define QSCALE 0.180336880f   // 1/sqrt(64) * log2(e)

__global__ __launch_bounds__(256) void qkv_gemm(const ushort* __restrict__ xb,
                                                const ushort* __restrict__ Wt,
                                                ushort* __restrict__ q,
                                                ushort* __restrict__ k,
                                                ushort* __restrict__ vt) {
    __shared__ ushort As[128 * 32];
    __shared__ ushort Bs[128 * 32];
    __shared__ ushort Eps[128][130];
    f32x4 acc[4][4];
    #pragma unroll
    for (int m = 0; m < 4; ++m)
        #pragma unroll
        for (int n = 0; n < 4; ++n)
            acc[m][n] = (f32x4){0.f, 0.f, 0.f, 0.f};

    const int wg = (blockIdx.x & 7) * 96 + (blockIdx.x >> 3);  // XCD swizzle
    const int tileM = (wg & 31) * 128;
    const int yy = wg >> 5;                   // 0..23
    const int wsel = yy >> 3;
    const int tileN = (yy & 7) * 128;
    const ushort* Bmat = Wt + (size_t)wsel * D_ * D_;

    gemm_tile(xb, Bmat, D_, tileM, tileN, As, Bs, acc);

    const int t = threadIdx.x;
    const int l = t & 63, w = t >> 6;
    const int wr = w >> 1, wc = w & 1;
    const int li = l & 15, lg = l >> 4;
    const float scale = (wsel == 0) ? QSCALE : 1.0f;

    // stage to LDS: Q/K row-major, V transposed ([col][row])
    if (wsel < 2) {
        #pragma unroll
        for (int m = 0; m < 4; ++m)
            #pragma unroll
            for (int n = 0; n < 4; ++n)
                #pragma unroll
                for (int r = 0; r < 4; ++r)
                    Eps[wr * 64 + m * 16 + lg * 4 + r][wc * 64 + n * 16 + li] =
                        bfbits(acc[m][n][r] * scale);
    } else {
        #pragma unroll
        for (int m = 0; m < 4; ++m)
            #pragma unroll
            for (int n = 0; n < 4; ++n)
                #pragma unroll
                for (int r = 0; r < 4; ++r)
                    Eps[wc * 64 + n * 16 + li][wr * 64 + m * 16 + lg * 4 + r] =
                        bfbits(acc[m][n][r]);
    }
    __syncthreads();

    const int rr = t >> 3;            // 0..31 (row group)
    const int cb = (t & 7) * 16;      // 0..112 (col base, ushorts)
    if (wsel < 2) {
        ushort* out = (wsel == 0) ? q : k;
        #pragma unroll
        for (int it = 0; it < 4; ++it) {
            const int row = it * 32 + rr;
            uint4 v0 = *(const uint4*)&Eps[row][cb];
            uint4 v1 = *(const uint4*)&Eps[row][cb + 8];
            size_t base = (size_t)(tileM + row) * D_ + tileN + cb;
            *(uint4*)&out[base] = v0;
            *(uint4*)&out[base + 8] = v1;
        }
    } else {
        const int b = tileM >> 11;            // 128-row tile never spans batch
        const int n0 = (tileM & (N_ - 1)) + cb;
        #pragma unroll
        for (int it = 0; it < 4; ++it) {
            const int row = it * 32 + rr;     // within-tile d index
            const int gcol = tileN + row;
            const int h = gcol >> 6, hd = gcol & 63;
            uint4 v0 = *(const uint4*)&Eps[row][cb];
            uint4 v1 = *(const uint4*)&Eps[row][cb + 8];
            size_t base = ((size_t)(b * H_ + h) * HD_ + hd) * N_ + n0;
            *(uint4*)&vt[base] = v0;
            *(uint4*)&vt[base + 8] = v1;
        }
    }
}

// ---------------------------------------------------------------------------
// Output projection: ctx[M][D] * Wo^T + bo -> fp32 out. grid 256 flat,
// XCD swizzle. Direct stores.
// ---------------------------------------------------------------------------
__global__ __launch_bounds__(256) void out_gemm(const ushort* __restrict__ ctx,
                                                const ushort* __restrict__ Wt,
                                                const float* __restrict__ bo,
                                                float* __restrict__ outp) {
    __shared__ ushort As[128 * 32];
    __shared__ ushort Bs[128 * 32];
    f32x4 acc[4][4];
    #pragma unroll
    for (int m = 0; m < 4; ++m)
        #pragma unroll
        for (int n = 0; n < 4; ++n)
            acc[m][n] = (f32x4){0.f, 0.f, 0.f, 0.f};

    const int wg = (blockIdx.x & 7) * 32 + (blockIdx.x >> 3);  // XCD swizzle
    const int tileM = (wg & 31) * 128;
    const int tileN = (wg >> 5) * 128;
    const ushort* Bmat = Wt + (size_t)3 * D_ * D_;   // Wo^T

    gemm_tile(ctx, Bmat, D_, tileM, tileN, As, Bs, acc);

    const int l = threadIdx.x & 63, w = threadIdx.x >> 6;
    const int wr = w >> 1, wc = w & 1;
    const int li = l & 15, lg = l >> 4;
    #pragma unroll
    for (int n = 0; n < 4; ++n) {
        float bias = bo[tileN + wc * 64 + n * 16 + li];
        #pragma unroll
        for (int m = 0; m < 4; ++m)
            #pragma unroll
            for (int r = 0; r < 4; ++r) {
                int grow = tileM + wr * 64 + m * 16 + lg * 4 + r;
                int gcol = tileN + wc * 64 + n * 16 + li;
                outp[(size_t)grow * D_ + gcol] = acc[m][n][r] + bias;
            }
    }
}

// ---------------------------------------------------------------------------
// MFMA causal flash attention, swapped-QK^T 16x16, dual q-tile per block
// (A: qt=p, B: qt=31-p), SHARED K/V FRAGMENT LOADS: kf[4][2] and vf[4][2]
// are read from LDS ONCE per step and feed BOTH streams' MFMAs (R11 read
// them twice -> 40% of LDS b128 reads eliminated; R15 showed per-CU pipe
// saturation, not occupancy, is binding).  kf/vf lifetimes disjoint.
// Fixed-scale softmax, lsum via MFMA-of-ones, per-stream Ps slot-XOR LDS.
// K/V [64][64] LDS dbuf, slot^(row&7) both-sides swizzle, 1 barrier/iter.
// grid 512 (16 pairs x 32 heads, XCD-swizzled).
// ---------------------------------------------------------------------------
__device__ __forceinline__ void softmax_store(f32x4 st[4], bool masked,
                                              int jkb, int qg,
                                              int li, int lg,
                                              ushort* PsW) {
    if (masked) {
        #pragma unroll
        for (int c = 0; c < 4; ++c)
            #pragma unroll
            for (int r = 0; r < 4; ++r) {
                const int kgl = jkb * 64 + c * 16 + lg * 4 + r;
                if (kgl > qg) st[c][r] = -INFINITY;
            }
    }
    const int sw = li & 7;
    #pragma unroll
    for (int c = 0; c < 4; ++c) {
        float p0 = exp2f(st[c][0]);
        float p1 = exp2f(st[c][1]);
        float p2 = exp2f(st[c][2]);
        float p3 = exp2f(st[c][3]);
        uint32_t w0, w1;
        asm("v_cvt_pk_bf16_f32 %0, %1, %2" : "=v"(w0) : "v"(p0), "v"(p1));
        asm("v_cvt_pk_bf16_f32 %0, %1, %2" : "=v"(w1) : "v"(p2), "v"(p3));
        uint2 pk; pk.x = w0; pk.y = w1;
        *(uint2*)&PsW[li * 64 + (((c * 2 + (lg >> 1)) ^ sw) << 3) + ((lg & 1) << 2)] = pk;
    }
}

__global__ __launch_bounds__(256, 2) void attn_fwd(const ushort* __restrict__ q,
                                                   const ushort* __restrict__ k,
                                                   const ushort* __restrict__ vt,
                                                   ushort* __restrict__ ctx) {
    __shared__ ushort Ks[2][4096];      // [buf][row*64 + slot*8], swizzled
    __shared__ ushort Vs[2][4096];
    __shared__ ushort PsA[4][1024];     // per-wave [16][64], slot-swizzled
    __shared__ ushort PsB[4][1024];

    const int t = threadIdx.x;
    const int l = t & 63;
    const int w = __builtin_amdgcn_readfirstlane(t >> 6);
    const int li = l & 15, lg = l >> 4;
    const int f = blockIdx.x;                        // 0..511
    const int bh = ((f & 7) << 2) | ((f >> 3) & 3);  // XCD i owns heads 4i..4i+3
    const int p = f >> 5;                            // 0..15
    const int qtA = p, qtB = 31 - p;
    const int b = bh >> 4, h = bh & 15;

    const ushort* Qg = q + ((size_t)b * N_) * D_ + h * 64;
    const ushort* Kg = k + ((size_t)b * N_) * D_ + h * 64;
    const ushort* Vg = vt + (size_t)bh * HD_ * N_;
    ushort* PsWA = &PsA[w][0];
    ushort* PsWB = &PsB[w][0];

    const int r8 = l >> 3;
    const int soff = ((l & 7) ^ r8) * 8;             // source slot offset
    const int rswz = li & 7;                         // read-side row xor
    const int sw = li & 7;

    const int qgA = qtA * 64 + w * 16 + li;
    const int qgB = qtB * 64 + w * 16 + li;

    bf16x8 bqA[2], bqB[2];
    #pragma unroll
    for (int tk = 0; tk < 2; ++tk) {
        bqA[tk] = *(const bf16x8*)&Qg[(size_t)qgA * D_ + tk * 32 + lg * 8];
        bqB[tk] = *(const bf16x8*)&Qg[(size_t)qgB * D_ + tk * 32 + lg * 8];
    }

    bf16x8 ones;
    #pragma unroll
    for (int i = 0; i < 8; ++i) ones[i] = (__bf16)1.0f;

    f32x4 odA[4], odB[4];
    #pragma unroll
    for (int db = 0; db < 4; ++db) {
        odA[db] = (f32x4){0.f, 0.f, 0.f, 0.f};
        odB[db] = (f32x4){0.f, 0.f, 0.f, 0.f};
    }
    f32x4 laccA = (f32x4){0.f, 0.f, 0.f, 0.f};
    f32x4 laccB = (f32x4){0.f, 0.f, 0.f, 0.f};

    // ---- prologue: stage tile 0 into buf 0
    #pragma unroll
    for (int i = 0; i < 2; ++i) {
        const int seg = w + i * 4;
        const int row = seg * 8 + r8;
        glds16(&Kg[(size_t)row * D_ + soff], &Ks[0][seg * 512]);
        glds16(&Vg[(size_t)row * N_ + soff], &Vs[0][seg * 512]);
    }
    __syncthreads();

    int cur = 0;
    for (int kb = 0; kb <= qtB; ++kb) {
        if (kb < qtB) {
            #pragma unroll
            for (int i = 0; i < 2; ++i) {
                const int seg = w + i * 4;
                const int row = seg * 8 + r8;
                glds16(&Kg[(size_t)((kb + 1) * 64 + row) * D_ + soff], &Ks[cur ^ 1][seg * 512]);
                glds16(&Vg[(size_t)row * N_ + (kb + 1) * 64 + soff], &Vs[cur ^ 1][seg * 512]);
            }
        }
        const bool actA = (kb <= qtA);

        // ---- K fragments: read ONCE, feed both streams
        {
            bf16x8 kf[4][2];
            #pragma unroll
            for (int c = 0; c < 4; ++c)
                #pragma unroll
                for (int tk = 0; tk < 2; ++tk)
                    kf[c][tk] = *(const bf16x8*)&Ks[cur][(c * 16 + li) * 64 +
                                                         (((tk * 4 + lg) ^ rswz) * 8)];
            f32x4 stB[4], stA[4];
            #pragma unroll
            for (int c = 0; c < 4; ++c) {
                stB[c] = (f32x4){0.f, 0.f, 0.f, 0.f};
                stB[c] = __builtin_amdgcn_mfma_f32_16x16x32_bf16(kf[c][0], bqB[0], stB[c], 0, 0, 0);
                stB[c] = __builtin_amdgcn_mfma_f32_16x16x32_bf16(kf[c][1], bqB[1], stB[c], 0, 0, 0);
            }
            if (actA) {
                #pragma unroll
                for (int c = 0; c < 4; ++c) {
                    stA[c] = (f32x4){0.f, 0.f, 0.f, 0.f};
                    stA[c] = __builtin_amdgcn_mfma_f32_16x16x32_bf16(kf[c][0], bqA[0], stA[c], 0, 0, 0);
                    stA[c] = __builtin_amdgcn_mfma_f32_16x16x32_bf16(kf[c][1], bqA[1], stA[c], 0, 0, 0);
                }
            }
            softmax_store(stB, kb == qtB, kb, qgB, li, lg, PsWB);
            if (actA) softmax_store(stA, kb == qtA, kb, qgA, li, lg, PsWA);
        }

        // ---- V fragments: read ONCE, feed both streams' PV
        {
            bf16x8 vf[4][2];
            #pragma unroll
            for (int db = 0; db < 4; ++db)
                #pragma unroll
                for (int tj = 0; tj < 2; ++tj)
                    vf[db][tj] = *(const bf16x8*)&Vs[cur][(db * 16 + li) * 64 +
                                                          (((tj * 4 + lg) ^ rswz) * 8)];
            #pragma unroll
            for (int tj = 0; tj < 2; ++tj) {
                bf16x8 paB = *(const bf16x8*)&PsWB[li * 64 + (((tj * 4 + lg) ^ sw) << 3)];
                laccB = __builtin_amdgcn_mfma_f32_16x16x32_bf16(paB, ones, laccB, 0, 0, 0);
                #pragma unroll
                for (int db = 0; db < 4; ++db)
                    odB[db] = __builtin_amdgcn_mfma_f32_16x16x32_bf16(paB, vf[db][tj], odB[db], 0, 0, 0);
            }
            if (actA) {
                #pragma unroll
                for (int tj = 0; tj < 2; ++tj) {
                    bf16x8 paA = *(const bf16x8*)&PsWA[li * 64 + (((tj * 4 + lg) ^ sw) << 3)];
                    laccA = __builtin_amdgcn_mfma_f32_16x16x32_bf16(paA, ones, laccA, 0, 0, 0);
                    #pragma unroll
                    for (int db = 0; db < 4; ++db)
                        odA[db] = __builtin_amdgcn_mfma_f32_16x16x32_bf16(paA, vf[db][tj], odA[db], 0, 0, 0);
                }
            }
        }

        __syncthreads();   // reads of buf[cur] done + prefetch landed
        cur ^= 1;
    }

    // epilogues: normalize, write ctx bf16 [M][D] heads interleaved
    #pragma unroll
    for (int r = 0; r < 4; ++r) {
        const float invA = 1.f / laccA[r];
        const int growA = qtA * 64 + w * 16 + lg * 4 + r;
        #pragma unroll
        for (int db = 0; db < 4; ++db)
            ctx[((size_t)(b * N_ + growA)) * D_ + h * 64 + db * 16 + li] = bfbits(odA[db][r] * invA);
        const float invB = 1.f / laccB[r];
        const int growB = qtB * 64 + w * 16 + lg * 4 + r;
        #pragma unroll
        for (int db = 0; db < 4; ++db)
            ctx[((size_t)(b * N_ + growB)) * D_ + h * 64 + db * 16 + li] = bfbits(odB[db][r] * invB);
    }
}

// ---------------------------------------------------------------------------
extern "C" void kernel_launch(void* const* d_in, const int* in_sizes, int n_in,
                              void* d_out, int out_size, void* d_ws, size_t ws_size,
                              hipStream_t stream) {
    (void)in_sizes; (void)n_in; (void)out_size; (void)ws_size;
    const float* x  = (const float*)d_in[0];
    const float* Wq = (const float*)d_in[1];
    const float* Wk = (const float*)d_in[2];
    const float* Wv = (const float*)d_in[3];
    const float* Wo = (const float*)d_in[4];
    const float* bo = (const float*)d_in[5];
    float* outp = (float*)d_out;

    ushort* xb  = (ushort*)d_ws;                       //  8 MB [M][D]
    ushort* Wt  = xb + (size_t)M_ * D_;                //  8 MB (4x 1024^2, n-major)
    ushort* qb  = Wt + (size_t)4 * D_ * D_;            //  8 MB [M][D]
    ushort* kb  = qb + (size_t)M_ * D_;                //  8 MB [M][D]
    ushort* vtb = kb + (size_t)M_ * D_;                //  8 MB [B,H,HD,N]
    ushort* ctx = vtb + (size_t)M_ * D_;               //  8 MB [M][D]

    prep<<<dim3(8192), 256, 0, stream>>>(x, Wq, Wk, Wv, Wo, xb, Wt);
    qkv_gemm<<<dim3(768), 256, 0, stream>>>(xb, Wt, qb, kb, vtb);
    attn_fwd<<<dim3(512), 256, 0, stream>>>(qb, kb, vtb, ctx);
    out_gemm<<<dim3(256), 256, 0, stream>>>(ctx, Wt, bo, outp);
}

// Round 17
// 107.194 us; speedup vs baseline: 1.0130x; 1.0130x over previous
//
#include <hip/hip_runtime.h>
#include <math.h>
#include <stdint.h>

#define B_ 2
#define N_ 2048
#define D_ 1024
#define H_ 16
#define HD_ 64
#define M_ (B_ * N_)   // 4096

typedef __bf16 bf16x8 __attribute__((ext_vector_type(8)));
typedef float f32x4 __attribute__((ext_vector_type(4)));

__device__ __forceinline__ ushort bfbits(float f) {
    __bf16 h = (__bf16)f;
    return __builtin_bit_cast(ushort, h);
}

// async global->LDS, 16B per lane; LDS dest = wave-uniform base + lane*16
__device__ __forceinline__ void glds16(const ushort* g, ushort* l) {
    __builtin_amdgcn_global_load_lds(
        (const __attribute__((address_space(1))) uint32_t*)g,
        (__attribute__((address_space(3))) uint32_t*)l, 16, 0, 0);
}

// ---------------------------------------------------------------------------
// Prep: cvt_x (blocks 0..4095) + cvt_w transpose (blocks 4096..8191).
// ---------------------------------------------------------------------------
__global__ __launch_bounds__(256) void prep(const float* __restrict__ x,
                                            const float* __restrict__ W0,
                                            const float* __restrict__ W1,
                                            const float* __restrict__ W2,
                                            const float* __restrict__ W3,
                                            ushort* __restrict__ xb,
                                            ushort* __restrict__ Wt) {
    __shared__ float T[32][33];
    const int t = threadIdx.x;
    int id = blockIdx.x;
    if (id < 4096) {
        int i = id * 256 + t;
        float4 v = ((const float4*)x)[i];
        ushort4 o;
        o.x = bfbits(v.x); o.y = bfbits(v.y); o.z = bfbits(v.z); o.w = bfbits(v.w);
        ((ushort4*)xb)[i] = o;
        return;
    }
    id -= 4096;
    const int z = id >> 10;
    const int k0 = (id & 31) * 32, n0 = ((id >> 5) & 31) * 32;
    const float* W = (z == 0) ? W0 : (z == 1) ? W1 : (z == 2) ? W2 : W3;
    ushort* out = Wt + (size_t)z * D_ * D_;
    {
        int kl = t >> 3, nl = (t & 7) * 4;
        float4 v = *(const float4*)&W[(size_t)(k0 + kl) * D_ + n0 + nl];
        T[kl][nl] = v.x; T[kl][nl + 1] = v.y; T[kl][nl + 2] = v.z; T[kl][nl + 3] = v.w;
    }
    __syncthreads();
    {
        int nl = t >> 3, k4 = (t & 7) * 4;
        ushort4 o;
        o.x = bfbits(T[k4 + 0][nl]); o.y = bfbits(T[k4 + 1][nl]);
        o.z = bfbits(T[k4 + 2][nl]); o.w = bfbits(T[k4 + 3][nl]);
        *(ushort4*)&out[(size_t)(n0 + nl) * D_ + k0 + k4] = o;
    }
}

// ---------------------------------------------------------------------------
// MFMA GEMM mainloop (m97 structure): 128x128 tile, BK=32, linear LDS
// [128][32] bf16 staged via global_load_lds w=16, both-sides XOR swizzle.
// ---------------------------------------------------------------------------
#define BK 32

__device__ __forceinline__ void gemm_tile(const ushort* __restrict__ A,
                                          const ushort* __restrict__ Bt,
                                          int K, int tileM, int tileN,
                                          ushort* As, ushort* Bs,
                                          f32x4 acc[4][4]) {
    const int t = threadIdx.x;
    const int l = t & 63;
    const int w = __builtin_amdgcn_readfirstlane(t >> 6);
    const int wr = w >> 1, wc = w & 1;
    const int li = l & 15, lg = l >> 4;
    const int lr = l >> 2;
    const int colu = (((l & 3) ^ (lr & 3)) << 3);   // inverse-swizzled src col
    const int swz = (li & 3) << 3;                   // read-side xor

    for (int k0 = 0; k0 < K; k0 += BK) {
        __syncthreads();
        #pragma unroll
        for (int it = 0; it < 2; ++it) {
            const int c2 = it * 4 + w;
            const int row = c2 * 16 + lr;
            glds16(&A[(size_t)(tileM + row) * K + k0 + colu], &As[c2 * 512]);
            glds16(&Bt[(size_t)(tileN + row) * K + k0 + colu], &Bs[c2 * 512]);
        }
        __syncthreads();
        bf16x8 a[4], b[4];
        #pragma unroll
        for (int m = 0; m < 4; ++m)
            a[m] = *(const bf16x8*)&As[(wr * 64 + m * 16 + li) * 32 + ((lg << 3) ^ swz)];
        #pragma unroll
        for (int n = 0; n < 4; ++n)
            b[n] = *(const bf16x8*)&Bs[(wc * 64 + n * 16 + li) * 32 + ((lg << 3) ^ swz)];
        #pragma unroll
        for (int m = 0; m < 4; ++m)
            #pragma unroll
            for (int n = 0; n < 4; ++n)
                acc[m][n] = __builtin_amdgcn_mfma_f32_16x16x32_bf16(a[m], b[n], acc[m][n], 0, 0, 0);
    }
}

// ---------------------------------------------------------------------------
// QKV projection. Q,K -> plain [M][D] bf16 (Q pre-scaled by 0.125*log2e);
// V -> [B,H,HD,N] transposed directly from the epilogue.
// grid 768 flat, bijective XCD swizzle (768%8==0).
// ---------------------------------------------------------------------------
#define QSCALE 0.180336880f   // 1/sqrt(64) * log2(e)

__global__ __launch_bounds__(256) void qkv_gemm(const ushort* __restrict__ xb,
                                                const ushort* __restrict__ Wt,
                                                ushort* __restrict__ q,
                                                ushort* __restrict__ k,
                                                ushort* __restrict__ vt) {
    __shared__ ushort As[128 * 32];
    __shared__ ushort Bs[128 * 32];
    __shared__ ushort Eps[128][130];
    f32x4 acc[4][4];
    #pragma unroll
    for (int m = 0; m < 4; ++m)
        #pragma unroll
        for (int n = 0; n < 4; ++n)
            acc[m][n] = (f32x4){0.f, 0.f, 0.f, 0.f};

    const int wg = (blockIdx.x & 7) * 96 + (blockIdx.x >> 3);  // XCD swizzle
    const int tileM = (wg & 31) * 128;
    const int yy = wg >> 5;                   // 0..23
    const int wsel = yy >> 3;
    const int tileN = (yy & 7) * 128;
    const ushort* Bmat = Wt + (size_t)wsel * D_ * D_;

    gemm_tile(xb, Bmat, D_, tileM, tileN, As, Bs, acc);

    const int t = threadIdx.x;
    const int l = t & 63, w = t >> 6;
    const int wr = w >> 1, wc = w & 1;
    const int li = l & 15, lg = l >> 4;
    const float scale = (wsel == 0) ? QSCALE : 1.0f;

    // stage to LDS: Q/K row-major, V transposed ([col][row])
    if (wsel < 2) {
        #pragma unroll
        for (int m = 0; m < 4; ++m)
            #pragma unroll
            for (int n = 0; n < 4; ++n)
                #pragma unroll
                for (int r = 0; r < 4; ++r)
                    Eps[wr * 64 + m * 16 + lg * 4 + r][wc * 64 + n * 16 + li] =
                        bfbits(acc[m][n][r] * scale);
    } else {
        #pragma unroll
        for (int m = 0; m < 4; ++m)
            #pragma unroll
            for (int n = 0; n < 4; ++n)
                #pragma unroll
                for (int r = 0; r < 4; ++r)
                    Eps[wc * 64 + n * 16 + li][wr * 64 + m * 16 + lg * 4 + r] =
                        bfbits(acc[m][n][r]);
    }
    __syncthreads();

    const int rr = t >> 3;            // 0..31 (row group)
    const int cb = (t & 7) * 16;      // 0..112 (col base, ushorts)
    if (wsel < 2) {
        ushort* out = (wsel == 0) ? q : k;
        #pragma unroll
        for (int it = 0; it < 4; ++it) {
            const int row = it * 32 + rr;
            uint4 v0 = *(const uint4*)&Eps[row][cb];
            uint4 v1 = *(const uint4*)&Eps[row][cb + 8];
            size_t base = (size_t)(tileM + row) * D_ + tileN + cb;
            *(uint4*)&out[base] = v0;
            *(uint4*)&out[base + 8] = v1;
        }
    } else {
        const int b = tileM >> 11;            // 128-row tile never spans batch
        const int n0 = (tileM & (N_ - 1)) + cb;
        #pragma unroll
        for (int it = 0; it < 4; ++it) {
            const int row = it * 32 + rr;     // within-tile d index
            const int gcol = tileN + row;
            const int h = gcol >> 6, hd = gcol & 63;
            uint4 v0 = *(const uint4*)&Eps[row][cb];
            uint4 v1 = *(const uint4*)&Eps[row][cb + 8];
            size_t base = ((size_t)(b * H_ + h) * HD_ + hd) * N_ + n0;
            *(uint4*)&vt[base] = v0;
            *(uint4*)&vt[base + 8] = v1;
        }
    }
}

// ---------------------------------------------------------------------------
// Output projection: ctx[M][D] * Wo^T + bo -> fp32 out. grid 256 flat,
// XCD swizzle. Direct stores.
// ---------------------------------------------------------------------------
__global__ __launch_bounds__(256) void out_gemm(const ushort* __restrict__ ctx,
                                                const ushort* __restrict__ Wt,
                                                const float* __restrict__ bo,
                                                float* __restrict__ outp) {
    __shared__ ushort As[128 * 32];
    __shared__ ushort Bs[128 * 32];
    f32x4 acc[4][4];
    #pragma unroll
    for (int m = 0; m < 4; ++m)
        #pragma unroll
        for (int n = 0; n < 4; ++n)
            acc[m][n] = (f32x4){0.f, 0.f, 0.f, 0.f};

    const int wg = (blockIdx.x & 7) * 32 + (blockIdx.x >> 3);  // XCD swizzle
    const int tileM = (wg & 31) * 128;
    const int tileN = (wg >> 5) * 128;
    const ushort* Bmat = Wt + (size_t)3 * D_ * D_;   // Wo^T

    gemm_tile(ctx, Bmat, D_, tileM, tileN, As, Bs, acc);

    const int l = threadIdx.x & 63, w = threadIdx.x >> 6;
    const int wr = w >> 1, wc = w & 1;
    const int li = l & 15, lg = l >> 4;
    #pragma unroll
    for (int n = 0; n < 4; ++n) {
        float bias = bo[tileN + wc * 64 + n * 16 + li];
        #pragma unroll
        for (int m = 0; m < 4; ++m)
            #pragma unroll
            for (int r = 0; r < 4; ++r) {
                int grow = tileM + wr * 64 + m * 16 + lg * 4 + r;
                int gcol = tileN + wc * 64 + n * 16 + li;
                outp[(size_t)grow * D_ + gcol] = acc[m][n][r] + bias;
            }
    }
}

// ---------------------------------------------------------------------------
// MFMA causal flash attention (R11 structure, best-known): swapped-QK^T
// 16x16, dual q-tile per block (A: qt=p, B: qt=31-p share K/V tiles),
// fixed-scale softmax, lsum via MFMA-of-ones, Ps slot-XOR LDS,
// K/V [64][64] LDS dbuf, slot^(row&7) swizzle, 1 barrier/iter.
// NEW: complementary-pair p remap — for f >= 256, p = 23 - (f>>5), so the
// two blocks round-robin-dispatched to one CU (f, f+256) get p and 15-p:
// per-CU block-steps = (32-p)+(32-(15-p)) = 49 CONSTANT (was 42..56, 33%
// imbalance; time was set by the 56-step CUs — R15/R16 neutrality + low
// average occupancy both fit that diagnosis).
// grid 512 (16 pairs x 32 heads, XCD-swizzled).
// ---------------------------------------------------------------------------
__device__ __forceinline__ void qk_mfma(f32x4 st[4], const ushort* Kb,
                                        const bf16x8 bq[2],
                                        int li, int lg, int rswz) {
    #pragma unroll
    for (int c = 0; c < 4; ++c) {
        st[c] = (f32x4){0.f, 0.f, 0.f, 0.f};
        #pragma unroll
        for (int tk = 0; tk < 2; ++tk) {
            bf16x8 kf = *(const bf16x8*)&Kb[(c * 16 + li) * 64 + (((tk * 4 + lg) ^ rswz) * 8)];
            st[c] = __builtin_amdgcn_mfma_f32_16x16x32_bf16(kf, bq[tk], st[c], 0, 0, 0);
        }
    }
}

__device__ __forceinline__ void softmax_pv(f32x4 st[4], const ushort* Vb,
                                           bool masked, int jkb, int qg,
                                           int li, int lg, int rswz,
                                           ushort* PsW, f32x4& lacc,
                                           f32x4 od[4], bf16x8 ones) {
    if (masked) {
        #pragma unroll
        for (int c = 0; c < 4; ++c)
            #pragma unroll
            for (int r = 0; r < 4; ++r) {
                const int kgl = jkb * 64 + c * 16 + lg * 4 + r;
                if (kgl > qg) st[c][r] = -INFINITY;
            }
    }
    const int sw = li & 7;
    #pragma unroll
    for (int c = 0; c < 4; ++c) {
        float p0 = exp2f(st[c][0]);
        float p1 = exp2f(st[c][1]);
        float p2 = exp2f(st[c][2]);
        float p3 = exp2f(st[c][3]);
        uint32_t w0, w1;
        asm("v_cvt_pk_bf16_f32 %0, %1, %2" : "=v"(w0) : "v"(p0), "v"(p1));
        asm("v_cvt_pk_bf16_f32 %0, %1, %2" : "=v"(w1) : "v"(p2), "v"(p3));
        uint2 pk; pk.x = w0; pk.y = w1;
        *(uint2*)&PsW[li * 64 + (((c * 2 + (lg >> 1)) ^ sw) << 3) + ((lg & 1) << 2)] = pk;
    }
    #pragma unroll
    for (int tj = 0; tj < 2; ++tj) {
        bf16x8 pa = *(const bf16x8*)&PsW[li * 64 + (((tj * 4 + lg) ^ sw) << 3)];
        lacc = __builtin_amdgcn_mfma_f32_16x16x32_bf16(pa, ones, lacc, 0, 0, 0);
        #pragma unroll
        for (int db = 0; db < 4; ++db) {
            bf16x8 bv = *(const bf16x8*)&Vb[(db * 16 + li) * 64 + (((tj * 4 + lg) ^ rswz) * 8)];
            od[db] = __builtin_amdgcn_mfma_f32_16x16x32_bf16(pa, bv, od[db], 0, 0, 0);
        }
    }
}

__global__ __launch_bounds__(256, 2) void attn_fwd(const ushort* __restrict__ q,
                                                   const ushort* __restrict__ k,
                                                   const ushort* __restrict__ vt,
                                                   ushort* __restrict__ ctx) {
    __shared__ ushort Ks[2][4096];      // [buf][row*64 + slot*8], swizzled
    __shared__ ushort Vs[2][4096];
    __shared__ ushort Ps[4][1024];      // per-wave [16][64], slot-swizzled

    const int t = threadIdx.x;
    const int l = t & 63;
    const int w = __builtin_amdgcn_readfirstlane(t >> 6);
    const int li = l & 15, lg = l >> 4;
    const int f = blockIdx.x;                        // 0..511
    const int bh = ((f & 7) << 2) | ((f >> 3) & 3);  // XCD i owns heads 4i..4i+3
    const int pr = f >> 5;                           // 0..15
    const int p = (f < 256) ? pr : (23 - pr);        // complementary pairing
    const int qtA = p, qtB = 31 - p;
    const int b = bh >> 4, h = bh & 15;

    const ushort* Qg = q + ((size_t)b * N_) * D_ + h * 64;
    const ushort* Kg = k + ((size_t)b * N_) * D_ + h * 64;
    const ushort* Vg = vt + (size_t)bh * HD_ * N_;
    ushort* PsW = &Ps[w][0];

    const int r8 = l >> 3;
    const int soff = ((l & 7) ^ r8) * 8;             // source slot offset
    const int rswz = li & 7;                         // read-side row xor

    const int qgA = qtA * 64 + w * 16 + li;
    const int qgB = qtB * 64 + w * 16 + li;

    bf16x8 bqA[2], bqB[2];
    #pragma unroll
    for (int tk = 0; tk < 2; ++tk) {
        bqA[tk] = *(const bf16x8*)&Qg[(size_t)qgA * D_ + tk * 32 + lg * 8];
        bqB[tk] = *(const bf16x8*)&Qg[(size_t)qgB * D_ + tk * 32 + lg * 8];
    }

    bf16x8 ones;
    #pragma unroll
    for (int i = 0; i < 8; ++i) ones[i] = (__bf16)1.0f;

    f32x4 odA[4], odB[4];
    #pragma unroll
    for (int db = 0; db < 4; ++db) {
        odA[db] = (f32x4){0.f, 0.f, 0.f, 0.f};
        odB[db] = (f32x4){0.f, 0.f, 0.f, 0.f};
    }
    f32x4 laccA = (f32x4){0.f, 0.f, 0.f, 0.f};
    f32x4 laccB = (f32x4){0.f, 0.f, 0.f, 0.f};

    // ---- prologue: stage tile 0 into buf 0
    #pragma unroll
    for (int i = 0; i < 2; ++i) {
        const int seg = w + i * 4;
        const int row = seg * 8 + r8;
        glds16(&Kg[(size_t)row * D_ + soff], &Ks[0][seg * 512]);
        glds16(&Vg[(size_t)row * N_ + soff], &Vs[0][seg * 512]);
    }
    __syncthreads();

    int cur = 0;
    for (int kb = 0; kb <= qtB; ++kb) {
        if (kb < qtB) {
            #pragma unroll
            for (int i = 0; i < 2; ++i) {
                const int seg = w + i * 4;
                const int row = seg * 8 + r8;
                glds16(&Kg[(size_t)((kb + 1) * 64 + row) * D_ + soff], &Ks[cur ^ 1][seg * 512]);
                glds16(&Vg[(size_t)row * N_ + (kb + 1) * 64 + soff], &Vs[cur ^ 1][seg * 512]);
            }
        }
        // stream B (always active)
        {
            f32x4 st[4];
            qk_mfma(st, Ks[cur], bqB, li, lg, rswz);
            softmax_pv(st, Vs[cur], kb == qtB, kb, qgB, li, lg, rswz, PsW, laccB, odB, ones);
        }
        // stream A (active while kb <= qtA) — independent chain = ILP
        if (kb <= qtA) {
            f32x4 st[4];
            qk_mfma(st, Ks[cur], bqA, li, lg, rswz);
            softmax_pv(st, Vs[cur], kb == qtA, kb, qgA, li, lg, rswz, PsW, laccA, odA, ones);
        }
        __syncthreads();   // reads of buf[cur] done + prefetch landed
        cur ^= 1;
    }

    // epilogues: normalize, write ctx bf16 [M][D] heads interleaved
    #pragma unroll
    for (int r = 0; r < 4; ++r) {
        const float invA = 1.f / laccA[r];
        const int growA = qtA * 64 + w * 16 + lg * 4 + r;
        #pragma unroll
        for (int db = 0; db < 4; ++db)
            ctx[((size_t)(b * N_ + growA)) * D_ + h * 64 + db * 16 + li] = bfbits(odA[db][r] * invA);
        const float invB = 1.f / laccB[r];
        const int growB = qtB * 64 + w * 16 + lg * 4 + r;
        #pragma unroll
        for (int db = 0; db < 4; ++db)
            ctx[((size_t)(b * N_ + growB)) * D_ + h * 64 + db * 16 + li] = bfbits(odB[db][r] * invB);
    }
}

// ---------------------------------------------------------------------------
extern "C" void kernel_launch(void* const* d_in, const int* in_sizes, int n_in,
                              void* d_out, int out_size, void* d_ws, size_t ws_size,
                              hipStream_t stream) {
    (void)in_sizes; (void)n_in; (void)out_size; (void)ws_size;
    const float* x  = (const float*)d_in[0];
    const float* Wq = (const float*)d_in[1];
    const float* Wk = (const float*)d_in[2];
    const float* Wv = (const float*)d_in[3];
    const float* Wo = (const float*)d_in[4];
    const float* bo = (const float*)d_in[5];
    float* outp = (float*)d_out;

    ushort* xb  = (ushort*)d_ws;                       //  8 MB [M][D]
    ushort* Wt  = xb + (size_t)M_ * D_;                //  8 MB (4x 1024^2, n-major)
    ushort* qb  = Wt + (size_t)4 * D_ * D_;            //  8 MB [M][D]
    ushort* kb  = qb + (size_t)M_ * D_;                //  8 MB [M][D]
    ushort* vtb = kb + (size_t)M_ * D_;                //  8 MB [B,H,HD,N]
    ushort* ctx = vtb + (size_t)M_ * D_;               //  8 MB [M][D]

    prep<<<dim3(8192), 256, 0, stream>>>(x, Wq, Wk, Wv, Wo, xb, Wt);
    qkv_gemm<<<dim3(768), 256, 0, stream>>>(xb, Wt, qb, kb, vtb);
    attn_fwd<<<dim3(512), 256, 0, stream>>>(qb, kb, vtb, ctx);
    out_gemm<<<dim3(256), 256, 0, stream>>>(ctx, Wt, bo, outp);
}

// Round 18
// 107.104 us; speedup vs baseline: 1.0138x; 1.0008x over previous
//
#include <hip/hip_runtime.h>
#include <math.h>
#include <stdint.h>

#define B_ 2
#define N_ 2048
#define D_ 1024
#define H_ 16
#define HD_ 64
#define M_ (B_ * N_)   // 4096

typedef __bf16 bf16x8 __attribute__((ext_vector_type(8)));
typedef float f32x4 __attribute__((ext_vector_type(4)));

__device__ __forceinline__ ushort bfbits(float f) {
    __bf16 h = (__bf16)f;
    return __builtin_bit_cast(ushort, h);
}

// async global->LDS, 16B per lane; LDS dest = wave-uniform base + lane*16
__device__ __forceinline__ void glds16(const ushort* g, ushort* l) {
    __builtin_amdgcn_global_load_lds(
        (const __attribute__((address_space(1))) uint32_t*)g,
        (__attribute__((address_space(3))) uint32_t*)l, 16, 0, 0);
}

// ---------------------------------------------------------------------------
// Prep: cvt_x (blocks 0..4095) + cvt_w transpose (blocks 4096..8191).
// ---------------------------------------------------------------------------
__global__ __launch_bounds__(256) void prep(const float* __restrict__ x,
                                            const float* __restrict__ W0,
                                            const float* __restrict__ W1,
                                            const float* __restrict__ W2,
                                            const float* __restrict__ W3,
                                            ushort* __restrict__ xb,
                                            ushort* __restrict__ Wt) {
    __shared__ float T[32][33];
    const int t = threadIdx.x;
    int id = blockIdx.x;
    if (id < 4096) {
        int i = id * 256 + t;
        float4 v = ((const float4*)x)[i];
        ushort4 o;
        o.x = bfbits(v.x); o.y = bfbits(v.y); o.z = bfbits(v.z); o.w = bfbits(v.w);
        ((ushort4*)xb)[i] = o;
        return;
    }
    id -= 4096;
    const int z = id >> 10;
    const int k0 = (id & 31) * 32, n0 = ((id >> 5) & 31) * 32;
    const float* W = (z == 0) ? W0 : (z == 1) ? W1 : (z == 2) ? W2 : W3;
    ushort* out = Wt + (size_t)z * D_ * D_;
    {
        int kl = t >> 3, nl = (t & 7) * 4;
        float4 v = *(const float4*)&W[(size_t)(k0 + kl) * D_ + n0 + nl];
        T[kl][nl] = v.x; T[kl][nl + 1] = v.y; T[kl][nl + 2] = v.z; T[kl][nl + 3] = v.w;
    }
    __syncthreads();
    {
        int nl = t >> 3, k4 = (t & 7) * 4;
        ushort4 o;
        o.x = bfbits(T[k4 + 0][nl]); o.y = bfbits(T[k4 + 1][nl]);
        o.z = bfbits(T[k4 + 2][nl]); o.w = bfbits(T[k4 + 3][nl]);
        *(ushort4*)&out[(size_t)(n0 + nl) * D_ + k0 + k4] = o;
    }
}

// ---------------------------------------------------------------------------
// MFMA GEMM mainloop (m97 structure): 128x128 tile, BK=32, linear LDS
// [128][32] bf16 staged via global_load_lds w=16, both-sides XOR swizzle.
// ---------------------------------------------------------------------------
#define BK 32

__device__ __forceinline__ void gemm_tile(const ushort* __restrict__ A,
                                          const ushort* __restrict__ Bt,
                                          int K, int tileM, int tileN,
                                          ushort* As, ushort* Bs,
                                          f32x4 acc[4][4]) {
    const int t = threadIdx.x;
    const int l = t & 63;
    const int w = __builtin_amdgcn_readfirstlane(t >> 6);
    const int wr = w >> 1, wc = w & 1;
    const int li = l & 15, lg = l >> 4;
    const int lr = l >> 2;
    const int colu = (((l & 3) ^ (lr & 3)) << 3);   // inverse-swizzled src col
    const int swz = (li & 3) << 3;                   // read-side xor

    for (int k0 = 0; k0 < K; k0 += BK) {
        __syncthreads();
        #pragma unroll
        for (int it = 0; it < 2; ++it) {
            const int c2 = it * 4 + w;
            const int row = c2 * 16 + lr;
            glds16(&A[(size_t)(tileM + row) * K + k0 + colu], &As[c2 * 512]);
            glds16(&Bt[(size_t)(tileN + row) * K + k0 + colu], &Bs[c2 * 512]);
        }
        __syncthreads();
        bf16x8 a[4], b[4];
        #pragma unroll
        for (int m = 0; m < 4; ++m)
            a[m] = *(const bf16x8*)&As[(wr * 64 + m * 16 + li) * 32 + ((lg << 3) ^ swz)];
        #pragma unroll
        for (int n = 0; n < 4; ++n)
            b[n] = *(const bf16x8*)&Bs[(wc * 64 + n * 16 + li) * 32 + ((lg << 3) ^ swz)];
        #pragma unroll
        for (int m = 0; m < 4; ++m)
            #pragma unroll
            for (int n = 0; n < 4; ++n)
                acc[m][n] = __builtin_amdgcn_mfma_f32_16x16x32_bf16(a[m], b[n], acc[m][n], 0, 0, 0);
    }
}

// ---------------------------------------------------------------------------
// QKV projection. Q,K -> plain [M][D] bf16 (Q pre-scaled by 0.125*log2e);
// V -> [B,H,HD,N] transposed directly from the epilogue.
// grid 768 flat, bijective XCD swizzle (768%8==0).
// ---------------------------------------------------------------------------
#define QSCALE 0.180336880f   // 1/sqrt(64) * log2(e)

__global__ __launch_bounds__(256) void qkv_gemm(const ushort* __restrict__ xb,
                                                const ushort* __restrict__ Wt,
                                                ushort* __restrict__ q,
                                                ushort* __restrict__ k,
                                                ushort* __restrict__ vt) {
    __shared__ ushort As[128 * 32];
    __shared__ ushort Bs[128 * 32];
    __shared__ ushort Eps[128][130];
    f32x4 acc[4][4];
    #pragma unroll
    for (int m = 0; m < 4; ++m)
        #pragma unroll
        for (int n = 0; n < 4; ++n)
            acc[m][n] = (f32x4){0.f, 0.f, 0.f, 0.f};

    const int wg = (blockIdx.x & 7) * 96 + (blockIdx.x >> 3);  // XCD swizzle
    const int tileM = (wg & 31) * 128;
    const int yy = wg >> 5;                   // 0..23
    const int wsel = yy >> 3;
    const int tileN = (yy & 7) * 128;
    const ushort* Bmat = Wt + (size_t)wsel * D_ * D_;

    gemm_tile(xb, Bmat, D_, tileM, tileN, As, Bs, acc);

    const int t = threadIdx.x;
    const int l = t & 63, w = t >> 6;
    const int wr = w >> 1, wc = w & 1;
    const int li = l & 15, lg = l >> 4;
    const float scale = (wsel == 0) ? QSCALE : 1.0f;

    // stage to LDS: Q/K row-major, V transposed ([col][row])
    if (wsel < 2) {
        #pragma unroll
        for (int m = 0; m < 4; ++m)
            #pragma unroll
            for (int n = 0; n < 4; ++n)
                #pragma unroll
                for (int r = 0; r < 4; ++r)
                    Eps[wr * 64 + m * 16 + lg * 4 + r][wc * 64 + n * 16 + li] =
                        bfbits(acc[m][n][r] * scale);
    } else {
        #pragma unroll
        for (int m = 0; m < 4; ++m)
            #pragma unroll
            for (int n = 0; n < 4; ++n)
                #pragma unroll
                for (int r = 0; r < 4; ++r)
                    Eps[wc * 64 + n * 16 + li][wr * 64 + m * 16 + lg * 4 + r] =
                        bfbits(acc[m][n][r]);
    }
    __syncthreads();

    const int rr = t >> 3;            // 0..31 (row group)
    const int cb = (t & 7) * 16;      // 0..112 (col base, ushorts)
    if (wsel < 2) {
        ushort* out = (wsel == 0) ? q : k;
        #pragma unroll
        for (int it = 0; it < 4; ++it) {
            const int row = it * 32 + rr;
            uint4 v0 = *(const uint4*)&Eps[row][cb];
            uint4 v1 = *(const uint4*)&Eps[row][cb + 8];
            size_t base = (size_t)(tileM + row) * D_ + tileN + cb;
            *(uint4*)&out[base] = v0;
            *(uint4*)&out[base + 8] = v1;
        }
    } else {
        const int b = tileM >> 11;            // 128-row tile never spans batch
        const int n0 = (tileM & (N_ - 1)) + cb;
        #pragma unroll
        for (int it = 0; it < 4; ++it) {
            const int row = it * 32 + rr;     // within-tile d index
            const int gcol = tileN + row;
            const int h = gcol >> 6, hd = gcol & 63;
            uint4 v0 = *(const uint4*)&Eps[row][cb];
            uint4 v1 = *(const uint4*)&Eps[row][cb + 8];
            size_t base = ((size_t)(b * H_ + h) * HD_ + hd) * N_ + n0;
            *(uint4*)&vt[base] = v0;
            *(uint4*)&vt[base + 8] = v1;
        }
    }
}

// ---------------------------------------------------------------------------
// Output projection: ctx[M][D] * Wo^T + bo -> fp32 out. grid 256 flat,
// XCD swizzle. Direct stores.
// ---------------------------------------------------------------------------
__global__ __launch_bounds__(256) void out_gemm(const ushort* __restrict__ ctx,
                                                const ushort* __restrict__ Wt,
                                                const float* __restrict__ bo,
                                                float* __restrict__ outp) {
    __shared__ ushort As[128 * 32];
    __shared__ ushort Bs[128 * 32];
    f32x4 acc[4][4];
    #pragma unroll
    for (int m = 0; m < 4; ++m)
        #pragma unroll
        for (int n = 0; n < 4; ++n)
            acc[m][n] = (f32x4){0.f, 0.f, 0.f, 0.f};

    const int wg = (blockIdx.x & 7) * 32 + (blockIdx.x >> 3);  // XCD swizzle
    const int tileM = (wg & 31) * 128;
    const int tileN = (wg >> 5) * 128;
    const ushort* Bmat = Wt + (size_t)3 * D_ * D_;   // Wo^T

    gemm_tile(ctx, Bmat, D_, tileM, tileN, As, Bs, acc);

    const int l = threadIdx.x & 63, w = threadIdx.x >> 6;
    const int wr = w >> 1, wc = w & 1;
    const int li = l & 15, lg = l >> 4;
    #pragma unroll
    for (int n = 0; n < 4; ++n) {
        float bias = bo[tileN + wc * 64 + n * 16 + li];
        #pragma unroll
        for (int m = 0; m < 4; ++m)
            #pragma unroll
            for (int r = 0; r < 4; ++r) {
                int grow = tileM + wr * 64 + m * 16 + lg * 4 + r;
                int gcol = tileN + wc * 64 + n * 16 + li;
                outp[(size_t)grow * D_ + gcol] = acc[m][n][r] + bias;
            }
    }
}

// ---------------------------------------------------------------------------
// MFMA causal flash attention, swapped-QK^T 16x16, dual q-tile per block
// (A: qt=p, B: qt=31-p), KVBLK=128: two 64-key sub-tiles per barrier-
// delimited iteration.  Halves barrier/step count (17-32 -> 9-16) and
// batches staging issue; 4 QK->SM->PV chains between barriers (2 sub-tiles
// x 2 streams).  All R11-verified per-subtile geometry kept bit-identical
// (sub-tiles live in separate [64][64] buffers).  Unconditional staging is
// bounds-safe (max staged tile = qtB+1 <= 31 -> rows <= 2047).
// Fixed-scale softmax, lsum via MFMA-of-ones, Ps slot-XOR LDS.
// LDS = 32K(K) + 32K(V) + 8K(Ps) = 72K -> 2 blocks/CU.
// grid 512; complementary p remap kept (harmless).
// ---------------------------------------------------------------------------
__device__ __forceinline__ void qk_mfma(f32x4 st[4], const ushort* Kb,
                                        const bf16x8 bq[2],
                                        int li, int lg, int rswz) {
    #pragma unroll
    for (int c = 0; c < 4; ++c) {
        st[c] = (f32x4){0.f, 0.f, 0.f, 0.f};
        #pragma unroll
        for (int tk = 0; tk < 2; ++tk) {
            bf16x8 kf = *(const bf16x8*)&Kb[(c * 16 + li) * 64 + (((tk * 4 + lg) ^ rswz) * 8)];
            st[c] = __builtin_amdgcn_mfma_f32_16x16x32_bf16(kf, bq[tk], st[c], 0, 0, 0);
        }
    }
}

__device__ __forceinline__ void softmax_pv(f32x4 st[4], const ushort* Vb,
                                           bool masked, int jkb, int qg,
                                           int li, int lg, int rswz,
                                           ushort* PsW, f32x4& lacc,
                                           f32x4 od[4], bf16x8 ones) {
    if (masked) {
        #pragma unroll
        for (int c = 0; c < 4; ++c)
            #pragma unroll
            for (int r = 0; r < 4; ++r) {
                const int kgl = jkb * 64 + c * 16 + lg * 4 + r;
                if (kgl > qg) st[c][r] = -INFINITY;
            }
    }
    const int sw = li & 7;
    #pragma unroll
    for (int c = 0; c < 4; ++c) {
        float p0 = exp2f(st[c][0]);
        float p1 = exp2f(st[c][1]);
        float p2 = exp2f(st[c][2]);
        float p3 = exp2f(st[c][3]);
        uint32_t w0, w1;
        asm("v_cvt_pk_bf16_f32 %0, %1, %2" : "=v"(w0) : "v"(p0), "v"(p1));
        asm("v_cvt_pk_bf16_f32 %0, %1, %2" : "=v"(w1) : "v"(p2), "v"(p3));
        uint2 pk; pk.x = w0; pk.y = w1;
        *(uint2*)&PsW[li * 64 + (((c * 2 + (lg >> 1)) ^ sw) << 3) + ((lg & 1) << 2)] = pk;
    }
    #pragma unroll
    for (int tj = 0; tj < 2; ++tj) {
        bf16x8 pa = *(const bf16x8*)&PsW[li * 64 + (((tj * 4 + lg) ^ sw) << 3)];
        lacc = __builtin_amdgcn_mfma_f32_16x16x32_bf16(pa, ones, lacc, 0, 0, 0);
        #pragma unroll
        for (int db = 0; db < 4; ++db) {
            bf16x8 bv = *(const bf16x8*)&Vb[(db * 16 + li) * 64 + (((tj * 4 + lg) ^ rswz) * 8)];
            od[db] = __builtin_amdgcn_mfma_f32_16x16x32_bf16(pa, bv, od[db], 0, 0, 0);
        }
    }
}

__global__ __launch_bounds__(256, 2) void attn_fwd(const ushort* __restrict__ q,
                                                   const ushort* __restrict__ k,
                                                   const ushort* __restrict__ vt,
                                                   ushort* __restrict__ ctx) {
    __shared__ ushort Ks[2][2][4096];   // [buf][subtile][row*64 + slot*8]
    __shared__ ushort Vs[2][2][4096];
    __shared__ ushort Ps[4][1024];      // per-wave [16][64], slot-swizzled

    const int t = threadIdx.x;
    const int l = t & 63;
    const int w = __builtin_amdgcn_readfirstlane(t >> 6);
    const int li = l & 15, lg = l >> 4;
    const int f = blockIdx.x;                        // 0..511
    const int bh = ((f & 7) << 2) | ((f >> 3) & 3);  // XCD i owns heads 4i..4i+3
    const int pr = f >> 5;                           // 0..15
    const int p = (f < 256) ? pr : (23 - pr);        // complementary pairing
    const int qtA = p, qtB = 31 - p;
    const int b = bh >> 4, h = bh & 15;

    const ushort* Qg = q + ((size_t)b * N_) * D_ + h * 64;
    const ushort* Kg = k + ((size_t)b * N_) * D_ + h * 64;
    const ushort* Vg = vt + (size_t)bh * HD_ * N_;
    ushort* PsW = &Ps[w][0];

    const int r8 = l >> 3;
    const int soff = ((l & 7) ^ r8) * 8;             // source slot offset
    const int rswz = li & 7;                         // read-side row xor

    const int qgA = qtA * 64 + w * 16 + li;
    const int qgB = qtB * 64 + w * 16 + li;

    bf16x8 bqA[2], bqB[2];
    #pragma unroll
    for (int tk = 0; tk < 2; ++tk) {
        bqA[tk] = *(const bf16x8*)&Qg[(size_t)qgA * D_ + tk * 32 + lg * 8];
        bqB[tk] = *(const bf16x8*)&Qg[(size_t)qgB * D_ + tk * 32 + lg * 8];
    }

    bf16x8 ones;
    #pragma unroll
    for (int i = 0; i < 8; ++i) ones[i] = (__bf16)1.0f;

    f32x4 odA[4], odB[4];
    #pragma unroll
    for (int db = 0; db < 4; ++db) {
        odA[db] = (f32x4){0.f, 0.f, 0.f, 0.f};
        odB[db] = (f32x4){0.f, 0.f, 0.f, 0.f};
    }
    f32x4 laccA = (f32x4){0.f, 0.f, 0.f, 0.f};
    f32x4 laccB = (f32x4){0.f, 0.f, 0.f, 0.f};

    const int nbig = (qtB + 2) >> 1;                 // big iterations

    // ---- prologue: stage subtiles 0,1 into buf 0
    #pragma unroll
    for (int s = 0; s < 2; ++s)
        #pragma unroll
        for (int i = 0; i < 2; ++i) {
            const int seg = w + i * 4;
            const int row = seg * 8 + r8;
            glds16(&Kg[(size_t)(s * 64 + row) * D_ + soff], &Ks[0][s][seg * 512]);
            glds16(&Vg[(size_t)row * N_ + s * 64 + soff], &Vs[0][s][seg * 512]);
        }
    __syncthreads();

    int cur = 0;
    for (int j = 0; j < nbig; ++j) {
        // stage next big tile (subtiles 2j+2, 2j+3) — bounds-safe unconditionally
        if (j + 1 < nbig) {
            #pragma unroll
            for (int s = 0; s < 2; ++s) {
                const int kt = 2 * (j + 1) + s;
                #pragma unroll
                for (int i = 0; i < 2; ++i) {
                    const int seg = w + i * 4;
                    const int row = seg * 8 + r8;
                    glds16(&Kg[(size_t)(kt * 64 + row) * D_ + soff], &Ks[cur ^ 1][s][seg * 512]);
                    glds16(&Vg[(size_t)row * N_ + kt * 64 + soff], &Vs[cur ^ 1][s][seg * 512]);
                }
            }
        }
        // 2 sub-tiles x 2 streams = 4 chains between barriers
        #pragma unroll
        for (int s = 0; s < 2; ++s) {
            const int kt = 2 * j + s;
            if (kt <= qtB) {
                f32x4 st[4];
                qk_mfma(st, Ks[cur][s], bqB, li, lg, rswz);
                softmax_pv(st, Vs[cur][s], kt == qtB, kt, qgB, li, lg, rswz, PsW, laccB, odB, ones);
            }
            if (kt <= qtA) {
                f32x4 st[4];
                qk_mfma(st, Ks[cur][s], bqA, li, lg, rswz);
                softmax_pv(st, Vs[cur][s], kt == qtA, kt, qgA, li, lg, rswz, PsW, laccA, odA, ones);
            }
        }
        __syncthreads();   // reads of buf[cur] done + prefetch landed
        cur ^= 1;
    }

    // epilogues: normalize, write ctx bf16 [M][D] heads interleaved
    #pragma unroll
    for (int r = 0; r < 4; ++r) {
        const float invA = 1.f / laccA[r];
        const int growA = qtA * 64 + w * 16 + lg * 4 + r;
        #pragma unroll
        for (int db = 0; db < 4; ++db)
            ctx[((size_t)(b * N_ + growA)) * D_ + h * 64 + db * 16 + li] = bfbits(odA[db][r] * invA);
        const float invB = 1.f / laccB[r];
        const int growB = qtB * 64 + w * 16 + lg * 4 + r;
        #pragma unroll
        for (int db = 0; db < 4; ++db)
            ctx[((size_t)(b * N_ + growB)) * D_ + h * 64 + db * 16 + li] = bfbits(odB[db][r] * invB);
    }
}

// ---------------------------------------------------------------------------
extern "C" void kernel_launch(void* const* d_in, const int* in_sizes, int n_in,
                              void* d_out, int out_size, void* d_ws, size_t ws_size,
                              hipStream_t stream) {
    (void)in_sizes; (void)n_in; (void)out_size; (void)ws_size;
    const float* x  = (const float*)d_in[0];
    const float* Wq = (const float*)d_in[1];
    const float* Wk = (const float*)d_in[2];
    const float* Wv = (const float*)d_in[3];
    const float* Wo = (const float*)d_in[4];
    const float* bo = (const float*)d_in[5];
    float* outp = (float*)d_out;

    ushort* xb  = (ushort*)d_ws;                       //  8 MB [M][D]
    ushort* Wt  = xb + (size_t)M_ * D_;                //  8 MB (4x 1024^2, n-major)
    ushort* qb  = Wt + (size_t)4 * D_ * D_;            //  8 MB [M][D]
    ushort* kb  = qb + (size_t)M_ * D_;                //  8 MB [M][D]
    ushort* vtb = kb + (size_t)M_ * D_;                //  8 MB [B,H,HD,N]
    ushort* ctx = vtb + (size_t)M_ * D_;               //  8 MB [M][D]

    prep<<<dim3(8192), 256, 0, stream>>>(x, Wq, Wk, Wv, Wo, xb, Wt);
    qkv_gemm<<<dim3(768), 256, 0, stream>>>(xb, Wt, qb, kb, vtb);
    attn_fwd<<<dim3(512), 256, 0, stream>>>(qb, kb, vtb, ctx);
    out_gemm<<<dim3(256), 256, 0, stream>>>(ctx, Wt, bo, outp);
}